// Round 2
// baseline (2706.847 us; speedup 1.0000x reference)
//
#include <hip/hip_runtime.h>

#define EDIM 128
#define NE   1024
#define RPB  64          // rows per block == block size (1 wave)

// Reproduces, bit-exactly, the numpy fp32 evaluation of
//   d = (sum(x*x,1,keepdims) + sum(W*W,1)) - 2*matmul(x, W.T)
//   idx = argmin(d, axis=1)  (first-index tie-break)
//   z_q = W[idx]
// Key semantics: final ops at |d|~128 quantize d to a 1.5e-5 grid; ties on
// that grid are resolved by FIRST INDEX. So we must match numpy's op order:
//  - sums: numpy pairwise 8-accumulator stride-8 pattern (n=128 <= PW_BLOCKSIZE)
//  - matmul: sgemm microkernel = sequential-k fused-multiply-add chain
//  - d: fl32(fl32(xx + wk2) - fl32(2*dot))

__global__ __launch_bounds__(64) void vq_fp32exact(
    const float* __restrict__ x, const float* __restrict__ W,
    float* __restrict__ zq, float* __restrict__ idxout)
{
#pragma clang fp contract(off)
    __shared__ float sx[RPB][EDIM + 1];   // stride 129: <=2-way bank alias (free)
    __shared__ float swsq[NE];
    __shared__ int   sbest[RPB];

    const int tid = threadIdx.x;
    const long long row0 = (long long)blockIdx.x * RPB;

    const float4* x4 = reinterpret_cast<const float4*>(x);
    const float4* W4 = reinterpret_cast<const float4*>(W);

    // ---- stage x tile (coalesced float4) ----
    for (int i = tid; i < RPB * (EDIM / 4); i += 64) {
        float4 v = x4[row0 * (EDIM / 4) + i];
        int r = i >> 5, c = (i & 31) << 2;
        sx[r][c] = v.x; sx[r][c + 1] = v.y; sx[r][c + 2] = v.z; sx[r][c + 3] = v.w;
    }

    // ---- swsq[k] = np.sum(W*W,1): numpy pairwise 8-acc pattern ----
    for (int k = tid; k < NE; k += 64) {
        const float4* wr = W4 + (size_t)k * (EDIM / 4);
        float4 A = wr[0], B = wr[1];
        float r0 = A.x * A.x, r1 = A.y * A.y, r2 = A.z * A.z, r3 = A.w * A.w;
        float r4 = B.x * B.x, r5 = B.y * B.y, r6 = B.z * B.z, r7 = B.w * B.w;
        #pragma unroll
        for (int i = 2; i < 32; i += 2) {
            float4 C = wr[i], D = wr[i + 1];
            r0 += C.x * C.x; r1 += C.y * C.y; r2 += C.z * C.z; r3 += C.w * C.w;
            r4 += D.x * D.x; r5 += D.y * D.y; r6 += D.z * D.z; r7 += D.w * D.w;
        }
        swsq[k] = ((r0 + r1) + (r2 + r3)) + ((r4 + r5) + (r6 + r7));
    }
    __syncthreads();

    // ---- xx = np.sum(x*x,1): same numpy pairwise 8-acc pattern ----
    float xxv;
    {
        const float* xr = sx[tid];
        float r0 = xr[0] * xr[0], r1 = xr[1] * xr[1], r2 = xr[2] * xr[2], r3 = xr[3] * xr[3];
        float r4 = xr[4] * xr[4], r5 = xr[5] * xr[5], r6 = xr[6] * xr[6], r7 = xr[7] * xr[7];
        #pragma unroll
        for (int i = 8; i < EDIM; i += 8) {
            r0 += xr[i] * xr[i];         r1 += xr[i + 1] * xr[i + 1];
            r2 += xr[i + 2] * xr[i + 2]; r3 += xr[i + 3] * xr[i + 3];
            r4 += xr[i + 4] * xr[i + 4]; r5 += xr[i + 5] * xr[i + 5];
            r6 += xr[i + 6] * xr[i + 6]; r7 += xr[i + 7] * xr[i + 7];
        }
        xxv = ((r0 + r1) + (r2 + r3)) + ((r4 + r5) + (r6 + r7));
    }

    // ---- argmin over k: dot = sequential-j fmaf chain (sgemm order) ----
    float dbest = 3.4e38f;
    int   bestk = 0;

    for (int k0 = 0; k0 < NE; k0 += 16) {
        float acc[16];
        #pragma unroll
        for (int c = 0; c < 16; ++c) acc[c] = 0.f;

        #pragma unroll 2
        for (int j = 0; j < EDIM; j += 4) {
            const float a0 = sx[tid][j];
            const float a1 = sx[tid][j + 1];
            const float a2 = sx[tid][j + 2];
            const float a3 = sx[tid][j + 3];
            #pragma unroll
            for (int c = 0; c < 16; ++c) {
                float4 w = W4[(size_t)(k0 + c) * (EDIM / 4) + (j >> 2)];  // wave-uniform
                acc[c] = fmaf(a0, w.x, acc[c]);   // fused: matches x86 vfmadd chain
                acc[c] = fmaf(a1, w.y, acc[c]);
                acc[c] = fmaf(a2, w.z, acc[c]);
                acc[c] = fmaf(a3, w.w, acc[c]);
            }
        }

        #pragma unroll
        for (int c = 0; c < 16; ++c) {
            float t1 = xxv + swsq[k0 + c];        // fl(xx + wk2)  (grid ~1.5e-5)
            float d  = t1 - (acc[c] + acc[c]);    // fl(t1 - fl(2*dot))
            if (d < dbest) { dbest = d; bestk = k0 + c; }  // strict <: first index wins
        }
    }

    sbest[tid] = bestk;
    idxout[row0 + tid] = (float)bestk;
    __syncthreads();

    // ---- z_q gather (coalesced float4; bit-exact copy of W rows) ----
    float4* zq4 = reinterpret_cast<float4*>(zq);
    for (int i = tid; i < RPB * (EDIM / 4); i += 64) {
        int r = i >> 5, c4 = (i & 31);
        zq4[row0 * (EDIM / 4) + i] = W4[(size_t)sbest[r] * (EDIM / 4) + c4];
    }
}

extern "C" void kernel_launch(void* const* d_in, const int* in_sizes, int n_in,
                              void* d_out, int out_size, void* d_ws, size_t ws_size,
                              hipStream_t stream) {
    (void)n_in; (void)out_size; (void)d_ws; (void)ws_size;
    const float* x = (const float*)d_in[0];
    const float* W = (const float*)d_in[1];
    const int Nrows = in_sizes[0] / EDIM;           // 262144

    float* zqp    = (float*)d_out;
    float* idxout = zqp + (size_t)Nrows * EDIM;     // indices stored as float values

    vq_fp32exact<<<dim3(Nrows / RPB), dim3(64), 0, stream>>>(x, W, zqp, idxout);
}

// Round 3
// 1795.670 us; speedup vs baseline: 1.5074x; 1.5074x over previous
//
#include <hip/hip_runtime.h>

#define EDIM 128
#define NE   1024
#define RPB  64          // rows per block == block size (1 wave)

// Bit-exact reproduction of numpy fp32:
//   d = (sum(x*x,1,keepdims) + sum(W*W,1)) - 2*matmul(x, W.T)
//   idx = argmin(d, 1) (first index on ties); z_q = W[idx]
// Semantics locked in round 2 (absmax 0.0):
//  - sums: numpy pairwise 8-accumulator stride-8 pattern, mul then add
//  - matmul: sequential-j fmaf chain per (row,k)
//  - d: fl32(fl32(xx + wk2) - fl32(2*dot)), strict < argmin
// Round-3 change: x row lives in VGPRs (no 33KB LDS tile) -> occupancy
// 1 -> 3 waves/SIMD; inner loop = register FMAs + scalar (wave-uniform)
// W loads only.

__global__ __launch_bounds__(64, 3) void vq_v3(
    const float* __restrict__ x, const float* __restrict__ W,
    float* __restrict__ zq, float* __restrict__ idxout)
{
#pragma clang fp contract(off)
    __shared__ float swsq[NE];        // 4 KB
    __shared__ int   sbest[RPB];      // 256 B

    const int tid = threadIdx.x;
    const long long row0 = (long long)blockIdx.x * RPB;
    const long long row  = row0 + tid;

    const float4* x4 = reinterpret_cast<const float4*>(x);
    const float4* W4 = reinterpret_cast<const float4*>(W);

    // ---- swsq[k] = np.sum(W*W,1): numpy pairwise 8-acc pattern (as round 2) ----
    for (int k = tid; k < NE; k += 64) {
        const float4* wr = W4 + (size_t)k * (EDIM / 4);
        float4 A = wr[0], B = wr[1];
        float r0 = A.x * A.x, r1 = A.y * A.y, r2 = A.z * A.z, r3 = A.w * A.w;
        float r4 = B.x * B.x, r5 = B.y * B.y, r6 = B.z * B.z, r7 = B.w * B.w;
        #pragma unroll
        for (int i = 2; i < 32; i += 2) {
            float4 C = wr[i], D = wr[i + 1];
            r0 += C.x * C.x; r1 += C.y * C.y; r2 += C.z * C.z; r3 += C.w * C.w;
            r4 += D.x * D.x; r5 += D.y * D.y; r6 += D.z * D.z; r7 += D.w * D.w;
        }
        swsq[k] = ((r0 + r1) + (r2 + r3)) + ((r4 + r5) + (r6 + r7));
    }

    // ---- stage this thread's x row into VGPRs (128 floats = 32 float4) ----
    float4 xr[32];
    #pragma unroll
    for (int i = 0; i < 32; ++i) xr[i] = x4[row * 32 + i];

    // ---- xx = np.sum(x*x,1): same pairwise 8-acc pattern, from registers ----
    float xxv;
    {
        float r0 = xr[0].x * xr[0].x, r1 = xr[0].y * xr[0].y;
        float r2 = xr[0].z * xr[0].z, r3 = xr[0].w * xr[0].w;
        float r4 = xr[1].x * xr[1].x, r5 = xr[1].y * xr[1].y;
        float r6 = xr[1].z * xr[1].z, r7 = xr[1].w * xr[1].w;
        #pragma unroll
        for (int i = 2; i < 32; i += 2) {
            r0 += xr[i].x * xr[i].x;     r1 += xr[i].y * xr[i].y;
            r2 += xr[i].z * xr[i].z;     r3 += xr[i].w * xr[i].w;
            r4 += xr[i + 1].x * xr[i + 1].x; r5 += xr[i + 1].y * xr[i + 1].y;
            r6 += xr[i + 1].z * xr[i + 1].z; r7 += xr[i + 1].w * xr[i + 1].w;
        }
        xxv = ((r0 + r1) + (r2 + r3)) + ((r4 + r5) + (r6 + r7));
    }
    __syncthreads();   // swsq ready

    // ---- argmin: 8 codes per group, j fully unrolled, pure reg FMA + s_load W ----
    float dbest = 3.4e38f;
    int   bestk = 0;

    for (int k0 = 0; k0 < NE; k0 += 8) {
        float acc[8];
        #pragma unroll
        for (int c = 0; c < 8; ++c) acc[c] = 0.f;

        #pragma unroll
        for (int j4 = 0; j4 < 32; ++j4) {
            const float4 a = xr[j4];
            #pragma unroll
            for (int c = 0; c < 8; ++c) {
                float4 w = W4[(size_t)(k0 + c) * 32 + j4];   // wave-uniform -> scalar pipe
                acc[c] = fmaf(a.x, w.x, acc[c]);
                acc[c] = fmaf(a.y, w.y, acc[c]);
                acc[c] = fmaf(a.z, w.z, acc[c]);
                acc[c] = fmaf(a.w, w.w, acc[c]);
            }
        }

        #pragma unroll
        for (int c = 0; c < 8; ++c) {
            float t1 = xxv + swsq[k0 + c];       // fl(xx + wk2)
            float d  = t1 - (acc[c] + acc[c]);   // fl(t1 - fl(2*dot))
            if (d < dbest) { dbest = d; bestk = k0 + c; }   // strict <: first index
        }
    }

    sbest[tid] = bestk;
    idxout[row] = (float)bestk;
    __syncthreads();

    // ---- z_q gather (coalesced float4; bit-exact copy of W rows) ----
    float4* zq4 = reinterpret_cast<float4*>(zq);
    for (int i = tid; i < RPB * (EDIM / 4); i += 64) {
        int r = i >> 5, c4 = (i & 31);
        zq4[row0 * (EDIM / 4) + i] = W4[(size_t)sbest[r] * (EDIM / 4) + c4];
    }
}

extern "C" void kernel_launch(void* const* d_in, const int* in_sizes, int n_in,
                              void* d_out, int out_size, void* d_ws, size_t ws_size,
                              hipStream_t stream) {
    (void)n_in; (void)out_size; (void)d_ws; (void)ws_size;
    const float* x = (const float*)d_in[0];
    const float* W = (const float*)d_in[1];
    const int Nrows = in_sizes[0] / EDIM;           // 262144

    float* zqp    = (float*)d_out;
    float* idxout = zqp + (size_t)Nrows * EDIM;     // indices stored as float values

    vq_v3<<<dim3(Nrows / RPB), dim3(64), 0, stream>>>(x, W, zqp, idxout);
}

// Round 4
// 1507.089 us; speedup vs baseline: 1.7961x; 1.1915x over previous
//
#include <hip/hip_runtime.h>

#define EDIM 128
#define NE   1024
#define RPB  64          // rows per block == block size (1 wave)

// Bit-exact reproduction of numpy fp32 (locked in round 2, absmax 0.0):
//   d = (sum(x*x,1,keepdims) + sum(W*W,1)) - 2*matmul(x, W.T)
//   idx = argmin(d,1) (first index on ties); z_q = W[idx]
//  - sums: numpy pairwise 8-accumulator stride-8 pattern, mul then add
//  - matmul: sequential-j fmaf chain per (row,k)
//  - d: fl32(fl32(xx + wk2) - fl32(2*dot)), strict < argmin
// Round-4 change: pin the x row into VGPRs with an empty-asm anti-remat
// fence (round 3: VGPR=84 proved the compiler re-loaded x from global in
// the hot loop -> FETCH 74 GB). Inner loop = reg FMAs + wave-uniform
// s_load W only.

__global__ __launch_bounds__(64, 2) void vq_v4(
    const float* __restrict__ x, const float* __restrict__ W,
    float* __restrict__ zq, float* __restrict__ idxout)
{
#pragma clang fp contract(off)
    __shared__ float swsq[NE];        // 4 KB
    __shared__ int   sbest[RPB];      // 256 B

    const int tid = threadIdx.x;
    const long long row0 = (long long)blockIdx.x * RPB;
    const long long row  = row0 + tid;

    const float4* x4 = reinterpret_cast<const float4*>(x);
    const float4* W4 = reinterpret_cast<const float4*>(W);

    // ---- stage this thread's x row into VGPRs (128 floats = 32 float4) ----
    float4 xr[32];
    #pragma unroll
    for (int i = 0; i < 32; ++i) xr[i] = x4[row * 32 + i];
    // Anti-rematerialization fence: each component becomes an opaque asm
    // result the compiler must keep live in a VGPR (cannot re-load from
    // memory). Zero-instruction asm.
    #pragma unroll
    for (int i = 0; i < 32; ++i)
        asm volatile("" : "+v"(xr[i].x), "+v"(xr[i].y), "+v"(xr[i].z), "+v"(xr[i].w));

    // ---- swsq[k] = np.sum(W*W,1): numpy pairwise 8-acc pattern ----
    for (int k = tid; k < NE; k += 64) {
        const float4* wr = W4 + (size_t)k * (EDIM / 4);
        float4 A = wr[0], B = wr[1];
        float r0 = A.x * A.x, r1 = A.y * A.y, r2 = A.z * A.z, r3 = A.w * A.w;
        float r4 = B.x * B.x, r5 = B.y * B.y, r6 = B.z * B.z, r7 = B.w * B.w;
        #pragma unroll
        for (int i = 2; i < 32; i += 2) {
            float4 C = wr[i], D = wr[i + 1];
            r0 += C.x * C.x; r1 += C.y * C.y; r2 += C.z * C.z; r3 += C.w * C.w;
            r4 += D.x * D.x; r5 += D.y * D.y; r6 += D.z * D.z; r7 += D.w * D.w;
        }
        swsq[k] = ((r0 + r1) + (r2 + r3)) + ((r4 + r5) + (r6 + r7));
    }

    // ---- xx = np.sum(x*x,1): same pairwise 8-acc pattern, from registers ----
    float xxv;
    {
        float r0 = xr[0].x * xr[0].x, r1 = xr[0].y * xr[0].y;
        float r2 = xr[0].z * xr[0].z, r3 = xr[0].w * xr[0].w;
        float r4 = xr[1].x * xr[1].x, r5 = xr[1].y * xr[1].y;
        float r6 = xr[1].z * xr[1].z, r7 = xr[1].w * xr[1].w;
        #pragma unroll
        for (int i = 2; i < 32; i += 2) {
            r0 += xr[i].x * xr[i].x;         r1 += xr[i].y * xr[i].y;
            r2 += xr[i].z * xr[i].z;         r3 += xr[i].w * xr[i].w;
            r4 += xr[i + 1].x * xr[i + 1].x; r5 += xr[i + 1].y * xr[i + 1].y;
            r6 += xr[i + 1].z * xr[i + 1].z; r7 += xr[i + 1].w * xr[i + 1].w;
        }
        xxv = ((r0 + r1) + (r2 + r3)) + ((r4 + r5) + (r6 + r7));
    }
    __syncthreads();   // swsq ready

    // ---- argmin: 8 codes per group, j fully unrolled, reg FMA + s_load W ----
    float dbest = 3.4e38f;
    int   bestk = 0;

    #pragma unroll 1
    for (int k0 = 0; k0 < NE; k0 += 8) {
        float acc[8];
        #pragma unroll
        for (int c = 0; c < 8; ++c) acc[c] = 0.f;

        #pragma unroll
        for (int j4 = 0; j4 < 32; ++j4) {
            const float4 a = xr[j4];
            #pragma unroll
            for (int c = 0; c < 8; ++c) {
                float4 w = W4[(size_t)(k0 + c) * 32 + j4];   // wave-uniform -> s_load
                acc[c] = fmaf(a.x, w.x, acc[c]);
                acc[c] = fmaf(a.y, w.y, acc[c]);
                acc[c] = fmaf(a.z, w.z, acc[c]);
                acc[c] = fmaf(a.w, w.w, acc[c]);
            }
        }

        #pragma unroll
        for (int c = 0; c < 8; ++c) {
            float t1 = xxv + swsq[k0 + c];       // fl(xx + wk2)
            float d  = t1 - (acc[c] + acc[c]);   // fl(t1 - fl(2*dot))
            if (d < dbest) { dbest = d; bestk = k0 + c; }   // strict <: first index
        }
    }

    sbest[tid] = bestk;
    idxout[row] = (float)bestk;
    __syncthreads();

    // ---- z_q gather (coalesced float4; bit-exact copy of W rows) ----
    float4* zq4 = reinterpret_cast<float4*>(zq);
    for (int i = tid; i < RPB * (EDIM / 4); i += 64) {
        int r = i >> 5, c4 = (i & 31);
        zq4[row0 * (EDIM / 4) + i] = W4[(size_t)sbest[r] * (EDIM / 4) + c4];
    }
}

extern "C" void kernel_launch(void* const* d_in, const int* in_sizes, int n_in,
                              void* d_out, int out_size, void* d_ws, size_t ws_size,
                              hipStream_t stream) {
    (void)n_in; (void)out_size; (void)d_ws; (void)ws_size;
    const float* x = (const float*)d_in[0];
    const float* W = (const float*)d_in[1];
    const int Nrows = in_sizes[0] / EDIM;           // 262144

    float* zqp    = (float*)d_out;
    float* idxout = zqp + (size_t)Nrows * EDIM;     // indices stored as float values

    vq_v4<<<dim3(Nrows / RPB), dim3(64), 0, stream>>>(x, W, zqp, idxout);
}